// Round 17
// baseline (293.852 us; speedup 1.0000x reference)
//
#include <hip/hip_runtime.h>

typedef __attribute__((ext_vector_type(8))) short bf16x8;
typedef __attribute__((ext_vector_type(4))) float f32x4;
typedef __attribute__((ext_vector_type(16))) float f32x16;

#define S_LEN  2048
#define HID    4096
#define NHEADS 32
#define NKVH   8
#define HDIM   128
#define QKVN   (HID + 2*NKVH*HDIM)   // 6144
#define KOFS   HID
#define VOFS   (HID + NKVH*HDIM)

#define AS1 __attribute__((address_space(1)))
#define AS3 __attribute__((address_space(3)))

__device__ __forceinline__ unsigned short f2bf(float f){
  unsigned int x = __float_as_uint(f);
  x += 0x7fffu + ((x >> 16) & 1u);
  return (unsigned short)(x >> 16);
}
__device__ __forceinline__ float bf2f(unsigned short h){
  return __uint_as_float(((unsigned int)h) << 16);
}

// ---- fused fp32->bf16 conversion (all 5 tensors) + RoPE table tail ----------
__global__ void cvt_all(const float* __restrict__ hs, const float* __restrict__ wq,
                        const float* __restrict__ wk, const float* __restrict__ wv,
                        const float* __restrict__ wo,
                        unsigned short* __restrict__ Hb,
                        unsigned short* __restrict__ Wqkvb,
                        unsigned short* __restrict__ Wob,
                        float* __restrict__ cosT, float* __restrict__ sinT){
  const int total = 12582912;
  const int totalAll = total + S_LEN*64;
  for (int i = blockIdx.x * blockDim.x + threadIdx.x; i < totalAll; i += gridDim.x * blockDim.x){
    if (i >= total){
      int idx = i - total;
      int s = idx >> 6, fi = idx & 63;
      float inv = expf(-(float)fi * (13.122363377404329f / 64.0f));
      float a = (float)s * inv;
      cosT[idx] = cosf(a);
      sinT[idx] = sinf(a);
      continue;
    }
    const float* src; unsigned short* dst;
    if (i < 2097152)      { src = hs + (size_t)i*4;             dst = Hb    + (size_t)i*4; }
    else if (i < 6291456) { size_t l = i - 2097152;  src = wq + l*4; dst = Wqkvb + l*4; }
    else if (i < 7340032) { size_t l = i - 6291456;  src = wk + l*4; dst = Wqkvb + 16777216 + l*4; }
    else if (i < 8388608) { size_t l = i - 7340032;  src = wv + l*4; dst = Wqkvb + 20971520 + l*4; }
    else                  { size_t l = i - 8388608;  src = wo + l*4; dst = Wob   + l*4; }
    float4 v = *(const float4*)src;
    ushort4 o;
    o.x = f2bf(v.x); o.y = f2bf(v.y); o.z = f2bf(v.z); o.w = f2bf(v.w);
    *(ushort4*)dst = o;
  }
}

// ---- merged V-transpose + Q/K RoPE (one launch; disjoint regions of QKVb) ---
__global__ __launch_bounds__(256) void trope(const float* __restrict__ cosT,
                                             const float* __restrict__ sinT,
                                             unsigned short* __restrict__ QKV,
                                             unsigned short* __restrict__ Vt){
  __shared__ unsigned short T[64][130];
  const int b = blockIdx.x;
  const int tid = threadIdx.x;
  if (b < 256){
    const int qt = b & 31, kvh = b >> 5;
    #pragma unroll
    for (int i=0;i<4;i++){
      int c = tid + i*256;
      int sl = c >> 4;
      int d0 = (c & 15) * 8;
      bf16x8 v = *(const bf16x8*)&QKV[(size_t)(qt*64+sl)*QKVN + VOFS + kvh*HDIM + d0];
      #pragma unroll
      for (int j=0;j<8;j++) T[sl][d0+j] = (unsigned short)v[j];
    }
    __syncthreads();
    #pragma unroll
    for (int i=0;i<4;i++){
      int c = tid + i*256;
      int d = c >> 3;
      int p0 = (c & 7) * 8;
      bf16x8 o;
      #pragma unroll
      for (int j=0;j<8;j++) o[j] = (short)T[p0+j][d];
      *(bf16x8*)&Vt[((size_t)kvh*HDIM + d)*S_LEN + qt*64 + p0] = o;
    }
    return;
  }
  const int totQ = S_LEN*NHEADS*64;
  const int total = totQ + S_LEN*NKVH*64;
  int idx = (b - 256) * 256 + tid;
  if (idx >= total) return;
  int nh, colofs, local;
  if (idx < totQ){ nh = NHEADS; colofs = 0;    local = idx; }
  else           { nh = NKVH;   colofs = KOFS; local = idx - totQ; }
  int i = local & 63;
  int h = (local >> 6) % nh;
  int s = local / (64*nh);
  size_t base = (size_t)s*QKVN + colofs + h*HDIM + i;
  float x0 = bf2f(QKV[base]), x1 = bf2f(QKV[base+64]);
  float c = cosT[(s<<6)|i], sn = sinT[(s<<6)|i];
  QKV[base]    = f2bf(x0*c - x1*sn);
  QKV[base+64] = f2bf(x1*c + x0*sn);
}

// ---- bf16 GEMM (r13 structure; QKV now 2Mx2N to halve A-frag duplication) --
// A and B staged via global_load_lds (full-spread XOR swizzle, 0 conflicts),
// double-buffered, one vmcnt(0)+barrier per K-tile, ALL fragment ds_reads
// issued before the MFMA clusters. Default block order (no XCD remap).
template<int BM, int BN, int WM, int WN, int OUTF32>
__global__ __launch_bounds__(256, 2) void gemm_fr(const unsigned short* __restrict__ A,
                                                  const unsigned short* __restrict__ W,
                                                  void* __restrict__ C, int M, int N, int K){
  constexpr int MF = (BM/WM)/16;
  constexpr int NF = (BN/WN)/16;
  constexpr int LA = BM/32;
  constexpr int LB = BN/32;
  constexpr int ABYTES = BM*128;
  constexpr int BBYTES = BN*128;
  __shared__ char lds_raw[2*ABYTES + 2*BBYTES];

  const int tid = threadIdx.x;
  const int lane = tid & 63, wv = tid >> 6;
  const int wm = wv / WN, wn = wv % WN;
  const int r = lane & 15, kq = lane >> 4;
  const int tn = blockIdx.x, tm = blockIdx.y;
  const unsigned short* Ab = A + (size_t)tm*BM*K;
  const unsigned short* Wb = W + (size_t)tn*BN*K;

  f32x4 acc[MF][NF];
  #pragma unroll
  for (int m=0;m<MF;m++)
    #pragma unroll
    for (int n=0;n<NF;n++) acc[m][n] = {0.f,0.f,0.f,0.f};

  auto swz = [](int row)->int { return ((row>>1)&3)<<1; };

  auto stage = [&](int buf, int kt){
    #pragma unroll
    for (int l=0;l<LA;l++){
      int c = l*256 + tid;
      int row = c >> 3, ch = c & 7;
      __builtin_amdgcn_global_load_lds(
        (const AS1 void*)(Ab + (size_t)row*K + kt + ((ch ^ swz(row))*8)),
        (AS3 void*)(lds_raw + buf*ABYTES + (l*256 + wv*64)*16), 16, 0, 0);
    }
    #pragma unroll
    for (int l=0;l<LB;l++){
      int c = l*256 + tid;
      int row = c >> 3, ch = c & 7;
      __builtin_amdgcn_global_load_lds(
        (const AS1 void*)(Wb + (size_t)row*K + kt + ((ch ^ swz(row))*8)),
        (AS3 void*)(lds_raw + 2*ABYTES + buf*BBYTES + (l*256 + wv*64)*16), 16, 0, 0);
    }
  };
  auto rdA = [&](int buf, int m, int kh)->bf16x8 {
    int row = wm*(BM/WM) + m*16 + r;
    int ch = (kh*4 + kq) ^ swz(row);
    return *(const bf16x8*)(lds_raw + buf*ABYTES + row*128 + ch*16);
  };
  auto rdB = [&](int buf, int n, int kh)->bf16x8 {
    int row = wn*(BN/WN) + n*16 + r;
    int ch = (kh*4 + kq) ^ swz(row);
    return *(const bf16x8*)(lds_raw + 2*ABYTES + buf*BBYTES + row*128 + ch*16);
  };

  const int nt = K/64;
  stage(0, 0);
  for (int t=0; t<nt; ++t){
    asm volatile("s_waitcnt vmcnt(0)" ::: "memory");
    __builtin_amdgcn_s_barrier();
    const int buf = t & 1;
    // issue ALL fragment reads (both kh-halves) before any MFMA
    bf16x8 av0[MF], bv0[NF], av1[MF], bv1[NF];
    #pragma unroll
    for (int m=0;m<MF;m++) av0[m] = rdA(buf, m, 0);
    #pragma unroll
    for (int n=0;n<NF;n++) bv0[n] = rdB(buf, n, 0);
    #pragma unroll
    for (int m=0;m<MF;m++) av1[m] = rdA(buf, m, 1);
    #pragma unroll
    for (int n=0;n<NF;n++) bv1[n] = rdB(buf, n, 1);
    // next-tile staging issues behind the ds_reads
    if (t+1 < nt) stage((t+1)&1, (t+1)*64);
    // kh0 cluster first (in-order lgkmcnt); kh1 reads + gloads drain underneath
    #pragma unroll
    for (int m=0;m<MF;m++)
      #pragma unroll
      for (int n=0;n<NF;n++)
        acc[m][n] = __builtin_amdgcn_mfma_f32_16x16x32_bf16(av0[m], bv0[n], acc[m][n], 0, 0, 0);
    #pragma unroll
    for (int m=0;m<MF;m++)
      #pragma unroll
      for (int n=0;n<NF;n++)
        acc[m][n] = __builtin_amdgcn_mfma_f32_16x16x32_bf16(av1[m], bv1[n], acc[m][n], 0, 0, 0);
  }

  #pragma unroll
  for (int m=0;m<MF;m++)
    #pragma unroll
    for (int n=0;n<NF;n++)
      #pragma unroll
      for (int j=0;j<4;j++){
        int gr = tm*BM + wm*(BM/WM) + m*16 + kq*4 + j;
        int gc = tn*BN + wn*(BN/WN) + n*16 + r;
        if (OUTF32) ((float*)C)[(size_t)gr*N + gc] = acc[m][n][j];
        else ((unsigned short*)C)[(size_t)gr*N + gc] = f2bf(acc[m][n][j]);
      }
}

// ---------------- attention v3b + T5 setprio around MFMA clusters ----------
__global__ __launch_bounds__(256, 2) void attn_fwd3(const unsigned short* __restrict__ QKV,
                                                    const unsigned short* __restrict__ Vt,
                                                    unsigned short* __restrict__ AO){
  __shared__ unsigned short Ks[2][64*128];
  __shared__ unsigned short Vs[2][128*64];
  __shared__ float Ls[4][32];
  const int tid = threadIdx.x;
  const int lane = tid & 63, wv = tid >> 6;
  const int bid = blockIdx.x;
  const int h = bid & 31;
  const int qt = (S_LEN/128 - 1) - (bid >> 5);
  const int kvh = h >> 2;
  const int qb = qt * 128;
  const int q0w = qb + wv * 32;
  const int l31 = lane & 31, g = lane >> 5;
  const int qg = q0w + l31;

  const float CS = 0.12751743f;
  const float C0 = 17.312340f;

  bf16x8 qf[8];
  #pragma unroll
  for (int st=0; st<8; ++st)
    qf[st] = *(const bf16x8*)&QKV[(size_t)qg*QKVN + h*HDIM + st*16 + g*8];

  f32x16 oacc[4];
  #pragma unroll
  for (int db=0; db<4; ++db)
    #pragma unroll
    for (int i=0;i<16;i++) oacc[db][i] = 0.f;
  float lsum = 0.f;

  const unsigned short* Kbase = QKV + KOFS + kvh*HDIM;
  const unsigned short* Vbase = Vt + (size_t)kvh*HDIM*S_LEN;

  auto stage = [&](int buf, int kv0){
    #pragma unroll
    for (int l=0; l<4; ++l){
      int c = l*256 + tid;
      int row = c >> 4, ch = c & 15;
      __builtin_amdgcn_global_load_lds(
        (const AS1 void*)(Kbase + (size_t)(kv0+row)*QKVN + ((ch ^ (row&15))*8)),
        (AS3 void*)((char*)&Ks[buf][0] + (l*256 + wv*64)*16), 16, 0, 0);
    }
    #pragma unroll
    for (int l=0; l<4; ++l){
      int c = l*256 + tid;
      int row = c >> 3, ch = c & 7;
      __builtin_amdgcn_global_load_lds(
        (const AS1 void*)(Vbase + (size_t)row*S_LEN + kv0 + ((ch ^ (row&7))*8)),
        (AS3 void*)((char*)&Vs[buf][0] + (l*256 + wv*64)*16), 16, 0, 0);
    }
  };

  const int nt = 2*qt + 2;
  stage(0, 0);
  for (int t=0; t<nt; ++t){
    __syncthreads();
    if (t+1 < nt) stage((t+1)&1, (t+1)*64);
    const int kv0 = t*64;
    if (kv0 > q0w + 31) continue;
    const unsigned short* K_ = &Ks[t&1][0];
    const unsigned short* V_ = &Vs[t&1][0];

    f32x16 a0, a1;
    #pragma unroll
    for (int i=0;i<16;i++){ a0[i]=0.f; a1[i]=0.f; }
    __builtin_amdgcn_s_setprio(1);
    #pragma unroll
    for (int st=0; st<8; ++st){
      int ch = (2*st + g) ^ (l31 & 15);
      bf16x8 k0 = *(const bf16x8*)&K_[ l31*128      + ch*8 ];
      int ch1 = (2*st + g) ^ ((32+l31) & 15);
      bf16x8 k1 = *(const bf16x8*)&K_[ (32+l31)*128 + ch1*8 ];
      a0 = __builtin_amdgcn_mfma_f32_32x32x16_bf16(k0, qf[st], a0, 0,0,0);
      a1 = __builtin_amdgcn_mfma_f32_32x32x16_bf16(k1, qf[st], a1, 0,0,0);
    }
    __builtin_amdgcn_s_setprio(0);

    float p0[16], p1[16];
    const bool dm = (kv0 + 63 > q0w);
    const int lim = qg - kv0 - 4*g;
    #pragma unroll
    for (int i=0;i<16;i++){
      const int co = (i&3) + 8*(i>>2);
      float e0 = fmaf(a0[i], CS, -C0);
      float e1 = fmaf(a1[i], CS, -C0);
      if (dm){
        if (co      > lim) e0 = -200.f;
        if (co + 32 > lim) e1 = -200.f;
      }
      p0[i] = exp2f(fminf(e0, 60.f));
      p1[i] = exp2f(fminf(e1, 60.f));
    }
    {
      float u0 = (p0[0]+p0[1])+(p0[2]+p0[3]);
      float u1 = (p0[4]+p0[5])+(p0[6]+p0[7]);
      float u2 = (p0[8]+p0[9])+(p0[10]+p0[11]);
      float u3 = (p0[12]+p0[13])+(p0[14]+p0[15]);
      float v0 = (p1[0]+p1[1])+(p1[2]+p1[3]);
      float v1 = (p1[4]+p1[5])+(p1[6]+p1[7]);
      float v2 = (p1[8]+p1[9])+(p1[10]+p1[11]);
      float v3 = (p1[12]+p1[13])+(p1[14]+p1[15]);
      lsum += ((u0+u1)+(u2+u3)) + ((v0+v1)+(v2+v3));
    }

    bf16x8 pa[4];
    #pragma unroll
    for (int u=0; u<4; ++u){
      const float* P = (u<2) ? p0 : p1;
      const int i0 = 8*(u&1);
      unsigned int w0,w1,w2,w3;
      asm("v_cvt_pk_bf16_f32 %0, %1, %2" : "=v"(w0) : "v"(P[i0+0]), "v"(P[i0+1]));
      asm("v_cvt_pk_bf16_f32 %0, %1, %2" : "=v"(w1) : "v"(P[i0+2]), "v"(P[i0+3]));
      asm("v_cvt_pk_bf16_f32 %0, %1, %2" : "=v"(w2) : "v"(P[i0+4]), "v"(P[i0+5]));
      asm("v_cvt_pk_bf16_f32 %0, %1, %2" : "=v"(w3) : "v"(P[i0+6]), "v"(P[i0+7]));
      unsigned int r0 = __shfl_xor(g ? w0 : w2, 32);
      unsigned int r1 = __shfl_xor(g ? w1 : w3, 32);
      union { unsigned int u4[4]; bf16x8 v; } pk;
      pk.u4[0] = g ? r0 : w0;
      pk.u4[1] = g ? r1 : w1;
      pk.u4[2] = g ? w2 : r0;
      pk.u4[3] = g ? w3 : r1;
      pa[u] = pk.v;
    }

    __builtin_amdgcn_s_setprio(1);
    #pragma unroll
    for (int u=0; u<4; ++u)
      #pragma unroll
      for (int db=0; db<4; ++db){
        int row = db*32 + l31;
        int ch = (2*u + g) ^ (row & 7);
        bf16x8 vb = *(const bf16x8*)&V_[row*64 + ch*8];
        oacc[db] = __builtin_amdgcn_mfma_f32_32x32x16_bf16(pa[u], vb, oacc[db], 0,0,0);
      }
    __builtin_amdgcn_s_setprio(0);
  }

  float ls = lsum + __shfl_xor(lsum, 32);
  float inv = 1.0f / fmaxf(ls, 1e-30f);
  Ls[wv][l31] = inv;
  #pragma unroll
  for (int ib=0; ib<4; ++ib){
    float4 iv = *(const float4*)&Ls[wv][8*ib + 4*g];
    float ivv[4] = {iv.x, iv.y, iv.z, iv.w};
    #pragma unroll
    for (int c3=0; c3<4; ++c3){
      int row = 8*ib + 4*g + c3;
      #pragma unroll
      for (int db=0; db<4; ++db){
        AO[(size_t)(qb + wv*32 + row)*HID + h*HDIM + db*32 + l31] =
          f2bf(oacc[db][4*ib+c3] * ivv[c3]);
      }
    }
  }
}

// ---------------- launch ----------------
extern "C" void kernel_launch(void* const* d_in, const int* in_sizes, int n_in,
                              void* d_out, int out_size, void* d_ws, size_t ws_size,
                              hipStream_t stream){
  (void)in_sizes; (void)n_in; (void)out_size; (void)ws_size;
  const float* hs = (const float*)d_in[0];
  const float* Wq = (const float*)d_in[1];
  const float* Wk = (const float*)d_in[2];
  const float* Wv = (const float*)d_in[3];
  const float* Wo = (const float*)d_in[4];
  float* out = (float*)d_out;
  char* ws = (char*)d_ws;
  size_t off = 0;
  auto alloc = [&](size_t bytes)->void*{ void* p = ws + off; off += (bytes + 255) & ~(size_t)255; return p; };

  unsigned short* Hb    = (unsigned short*)alloc((size_t)S_LEN*HID*2);
  unsigned short* Wqkvb = (unsigned short*)alloc((size_t)QKVN*HID*2);
  unsigned short* Wob   = (unsigned short*)alloc((size_t)HID*HID*2);
  unsigned short* QKVb  = (unsigned short*)alloc((size_t)S_LEN*QKVN*2);
  unsigned short* AOb   = (unsigned short*)alloc((size_t)S_LEN*HID*2);
  unsigned short* Vtb   = (unsigned short*)alloc((size_t)NKVH*HDIM*S_LEN*2);
  float* cosT = (float*)alloc((size_t)S_LEN*64*4);
  float* sinT = (float*)alloc((size_t)S_LEN*64*4);

  // fused conversion of all inputs + rope table (one launch, grid-stride)
  cvt_all<<<2048, 256, 0, stream>>>(hs, Wq, Wk, Wv, Wo, Hb, Wqkvb, Wob, cosT, sinT);

  // fused QKV projection: BM=128, BN=192, 4 waves 2Mx2N (A-dup 2x) -> 512 blocks (2/CU)
  gemm_fr<128,192,2,2,0><<<dim3(QKVN/192, S_LEN/128), 256, 0, stream>>>(Hb, Wqkvb, QKVb, S_LEN, QKVN, HID);

  // merged V-transpose (blocks 0..255) + Q/K rope (blocks 256..)
  {
    int total = S_LEN*NHEADS*64 + S_LEN*NKVH*64;
    int ropeBlocks = (total + 255) / 256;
    trope<<<256 + ropeBlocks, 256, 0, stream>>>(cosT, sinT, QKVb, Vtb);
  }

  // attention: 16 q-tiles of 128 (descending) x 32 heads = 512 blocks
  attn_fwd3<<<dim3(512), 256, 0, stream>>>(QKVb, Vtb, AOb);

  // output projection: BM=128, BN=128, 4 waves 2Mx2N -> 512 blocks (2/CU)
  gemm_fr<128,128,2,2,1><<<dim3(HID/128, S_LEN/128), 256, 0, stream>>>(AOb, Wob, out, S_LEN, HID, HID);
}

// Round 18
// 281.249 us; speedup vs baseline: 1.0448x; 1.0448x over previous
//
#include <hip/hip_runtime.h>

typedef __attribute__((ext_vector_type(8))) short bf16x8;
typedef __attribute__((ext_vector_type(4))) float f32x4;
typedef __attribute__((ext_vector_type(16))) float f32x16;

#define S_LEN  2048
#define HID    4096
#define NHEADS 32
#define NKVH   8
#define HDIM   128
#define QKVN   (HID + 2*NKVH*HDIM)   // 6144
#define KOFS   HID
#define VOFS   (HID + NKVH*HDIM)

#define AS1 __attribute__((address_space(1)))
#define AS3 __attribute__((address_space(3)))

__device__ __forceinline__ unsigned short f2bf(float f){
  unsigned int x = __float_as_uint(f);
  x += 0x7fffu + ((x >> 16) & 1u);
  return (unsigned short)(x >> 16);
}
__device__ __forceinline__ float bf2f(unsigned short h){
  return __uint_as_float(((unsigned int)h) << 16);
}

// ---- fused fp32->bf16 conversion (all 5 tensors) + RoPE table tail ----------
__global__ void cvt_all(const float* __restrict__ hs, const float* __restrict__ wq,
                        const float* __restrict__ wk, const float* __restrict__ wv,
                        const float* __restrict__ wo,
                        unsigned short* __restrict__ Hb,
                        unsigned short* __restrict__ Wqkvb,
                        unsigned short* __restrict__ Wob,
                        float* __restrict__ cosT, float* __restrict__ sinT){
  const int total = 12582912;
  const int totalAll = total + S_LEN*64;
  for (int i = blockIdx.x * blockDim.x + threadIdx.x; i < totalAll; i += gridDim.x * blockDim.x){
    if (i >= total){
      int idx = i - total;
      int s = idx >> 6, fi = idx & 63;
      float inv = expf(-(float)fi * (13.122363377404329f / 64.0f));
      float a = (float)s * inv;
      cosT[idx] = cosf(a);
      sinT[idx] = sinf(a);
      continue;
    }
    const float* src; unsigned short* dst;
    if (i < 2097152)      { src = hs + (size_t)i*4;             dst = Hb    + (size_t)i*4; }
    else if (i < 6291456) { size_t l = i - 2097152;  src = wq + l*4; dst = Wqkvb + l*4; }
    else if (i < 7340032) { size_t l = i - 6291456;  src = wk + l*4; dst = Wqkvb + 16777216 + l*4; }
    else if (i < 8388608) { size_t l = i - 7340032;  src = wv + l*4; dst = Wqkvb + 20971520 + l*4; }
    else                  { size_t l = i - 8388608;  src = wo + l*4; dst = Wob   + l*4; }
    float4 v = *(const float4*)src;
    ushort4 o;
    o.x = f2bf(v.x); o.y = f2bf(v.y); o.z = f2bf(v.z); o.w = f2bf(v.w);
    *(ushort4*)dst = o;
  }
}

// ---- merged V-transpose + Q/K RoPE (one launch; disjoint regions of QKVb) ---
__global__ __launch_bounds__(256) void trope(const float* __restrict__ cosT,
                                             const float* __restrict__ sinT,
                                             unsigned short* __restrict__ QKV,
                                             unsigned short* __restrict__ Vt){
  __shared__ unsigned short T[64][130];
  const int b = blockIdx.x;
  const int tid = threadIdx.x;
  if (b < 256){
    const int qt = b & 31, kvh = b >> 5;
    #pragma unroll
    for (int i=0;i<4;i++){
      int c = tid + i*256;
      int sl = c >> 4;
      int d0 = (c & 15) * 8;
      bf16x8 v = *(const bf16x8*)&QKV[(size_t)(qt*64+sl)*QKVN + VOFS + kvh*HDIM + d0];
      #pragma unroll
      for (int j=0;j<8;j++) T[sl][d0+j] = (unsigned short)v[j];
    }
    __syncthreads();
    #pragma unroll
    for (int i=0;i<4;i++){
      int c = tid + i*256;
      int d = c >> 3;
      int p0 = (c & 7) * 8;
      bf16x8 o;
      #pragma unroll
      for (int j=0;j<8;j++) o[j] = (short)T[p0+j][d];
      *(bf16x8*)&Vt[((size_t)kvh*HDIM + d)*S_LEN + qt*64 + p0] = o;
    }
    return;
  }
  const int totQ = S_LEN*NHEADS*64;
  const int total = totQ + S_LEN*NKVH*64;
  int idx = (b - 256) * 256 + tid;
  if (idx >= total) return;
  int nh, colofs, local;
  if (idx < totQ){ nh = NHEADS; colofs = 0;    local = idx; }
  else           { nh = NKVH;   colofs = KOFS; local = idx - totQ; }
  int i = local & 63;
  int h = (local >> 6) % nh;
  int s = local / (64*nh);
  size_t base = (size_t)s*QKVN + colofs + h*HDIM + i;
  float x0 = bf2f(QKV[base]), x1 = bf2f(QKV[base+64]);
  float c = cosT[(s<<6)|i], sn = sinT[(s<<6)|i];
  QKV[base]    = f2bf(x0*c - x1*sn);
  QKV[base+64] = f2bf(x1*c + x0*sn);
}

// ---- bf16 GEMM (r13 structure; QKV 2Mx2N — r17-verified win) ---------------
// A and B staged via global_load_lds (full-spread XOR swizzle, 0 conflicts),
// double-buffered, one vmcnt(0)+barrier per K-tile, ALL fragment ds_reads
// issued before the MFMA clusters. Default block order (no XCD remap).
template<int BM, int BN, int WM, int WN, int OUTF32>
__global__ __launch_bounds__(256, 2) void gemm_fr(const unsigned short* __restrict__ A,
                                                  const unsigned short* __restrict__ W,
                                                  void* __restrict__ C, int M, int N, int K){
  constexpr int MF = (BM/WM)/16;
  constexpr int NF = (BN/WN)/16;
  constexpr int LA = BM/32;
  constexpr int LB = BN/32;
  constexpr int ABYTES = BM*128;
  constexpr int BBYTES = BN*128;
  __shared__ char lds_raw[2*ABYTES + 2*BBYTES];

  const int tid = threadIdx.x;
  const int lane = tid & 63, wv = tid >> 6;
  const int wm = wv / WN, wn = wv % WN;
  const int r = lane & 15, kq = lane >> 4;
  const int tn = blockIdx.x, tm = blockIdx.y;
  const unsigned short* Ab = A + (size_t)tm*BM*K;
  const unsigned short* Wb = W + (size_t)tn*BN*K;

  f32x4 acc[MF][NF];
  #pragma unroll
  for (int m=0;m<MF;m++)
    #pragma unroll
    for (int n=0;n<NF;n++) acc[m][n] = {0.f,0.f,0.f,0.f};

  auto swz = [](int row)->int { return ((row>>1)&3)<<1; };

  auto stage = [&](int buf, int kt){
    #pragma unroll
    for (int l=0;l<LA;l++){
      int c = l*256 + tid;
      int row = c >> 3, ch = c & 7;
      __builtin_amdgcn_global_load_lds(
        (const AS1 void*)(Ab + (size_t)row*K + kt + ((ch ^ swz(row))*8)),
        (AS3 void*)(lds_raw + buf*ABYTES + (l*256 + wv*64)*16), 16, 0, 0);
    }
    #pragma unroll
    for (int l=0;l<LB;l++){
      int c = l*256 + tid;
      int row = c >> 3, ch = c & 7;
      __builtin_amdgcn_global_load_lds(
        (const AS1 void*)(Wb + (size_t)row*K + kt + ((ch ^ swz(row))*8)),
        (AS3 void*)(lds_raw + 2*ABYTES + buf*BBYTES + (l*256 + wv*64)*16), 16, 0, 0);
    }
  };
  auto rdA = [&](int buf, int m, int kh)->bf16x8 {
    int row = wm*(BM/WM) + m*16 + r;
    int ch = (kh*4 + kq) ^ swz(row);
    return *(const bf16x8*)(lds_raw + buf*ABYTES + row*128 + ch*16);
  };
  auto rdB = [&](int buf, int n, int kh)->bf16x8 {
    int row = wn*(BN/WN) + n*16 + r;
    int ch = (kh*4 + kq) ^ swz(row);
    return *(const bf16x8*)(lds_raw + 2*ABYTES + buf*BBYTES + row*128 + ch*16);
  };

  const int nt = K/64;
  stage(0, 0);
  for (int t=0; t<nt; ++t){
    asm volatile("s_waitcnt vmcnt(0)" ::: "memory");
    __builtin_amdgcn_s_barrier();
    const int buf = t & 1;
    // issue ALL fragment reads (both kh-halves) before any MFMA
    bf16x8 av0[MF], bv0[NF], av1[MF], bv1[NF];
    #pragma unroll
    for (int m=0;m<MF;m++) av0[m] = rdA(buf, m, 0);
    #pragma unroll
    for (int n=0;n<NF;n++) bv0[n] = rdB(buf, n, 0);
    #pragma unroll
    for (int m=0;m<MF;m++) av1[m] = rdA(buf, m, 1);
    #pragma unroll
    for (int n=0;n<NF;n++) bv1[n] = rdB(buf, n, 1);
    // next-tile staging issues behind the ds_reads
    if (t+1 < nt) stage((t+1)&1, (t+1)*64);
    // kh0 cluster first (in-order lgkmcnt); kh1 reads + gloads drain underneath
    #pragma unroll
    for (int m=0;m<MF;m++)
      #pragma unroll
      for (int n=0;n<NF;n++)
        acc[m][n] = __builtin_amdgcn_mfma_f32_16x16x32_bf16(av0[m], bv0[n], acc[m][n], 0, 0, 0);
    #pragma unroll
    for (int m=0;m<MF;m++)
      #pragma unroll
      for (int n=0;n<NF;n++)
        acc[m][n] = __builtin_amdgcn_mfma_f32_16x16x32_bf16(av1[m], bv1[n], acc[m][n], 0, 0, 0);
  }

  #pragma unroll
  for (int m=0;m<MF;m++)
    #pragma unroll
    for (int n=0;n<NF;n++)
      #pragma unroll
      for (int j=0;j<4;j++){
        int gr = tm*BM + wm*(BM/WM) + m*16 + kq*4 + j;
        int gc = tn*BN + wn*(BN/WN) + n*16 + r;
        if (OUTF32) ((float*)C)[(size_t)gr*N + gc] = acc[m][n][j];
        else ((unsigned short*)C)[(size_t)gr*N + gc] = f2bf(acc[m][n][j]);
      }
}

// ---------------- attention v3b (r16 version — setprio reverted) ------------
__global__ __launch_bounds__(256, 2) void attn_fwd3(const unsigned short* __restrict__ QKV,
                                                    const unsigned short* __restrict__ Vt,
                                                    unsigned short* __restrict__ AO){
  __shared__ unsigned short Ks[2][64*128];
  __shared__ unsigned short Vs[2][128*64];
  __shared__ float Ls[4][32];
  const int tid = threadIdx.x;
  const int lane = tid & 63, wv = tid >> 6;
  const int bid = blockIdx.x;
  const int h = bid & 31;
  const int qt = (S_LEN/128 - 1) - (bid >> 5);
  const int kvh = h >> 2;
  const int qb = qt * 128;
  const int q0w = qb + wv * 32;
  const int l31 = lane & 31, g = lane >> 5;
  const int qg = q0w + l31;

  const float CS = 0.12751743f;
  const float C0 = 17.312340f;

  bf16x8 qf[8];
  #pragma unroll
  for (int st=0; st<8; ++st)
    qf[st] = *(const bf16x8*)&QKV[(size_t)qg*QKVN + h*HDIM + st*16 + g*8];

  f32x16 oacc[4];
  #pragma unroll
  for (int db=0; db<4; ++db)
    #pragma unroll
    for (int i=0;i<16;i++) oacc[db][i] = 0.f;
  float lsum = 0.f;

  const unsigned short* Kbase = QKV + KOFS + kvh*HDIM;
  const unsigned short* Vbase = Vt + (size_t)kvh*HDIM*S_LEN;

  auto stage = [&](int buf, int kv0){
    #pragma unroll
    for (int l=0; l<4; ++l){
      int c = l*256 + tid;
      int row = c >> 4, ch = c & 15;
      __builtin_amdgcn_global_load_lds(
        (const AS1 void*)(Kbase + (size_t)(kv0+row)*QKVN + ((ch ^ (row&15))*8)),
        (AS3 void*)((char*)&Ks[buf][0] + (l*256 + wv*64)*16), 16, 0, 0);
    }
    #pragma unroll
    for (int l=0; l<4; ++l){
      int c = l*256 + tid;
      int row = c >> 3, ch = c & 7;
      __builtin_amdgcn_global_load_lds(
        (const AS1 void*)(Vbase + (size_t)row*S_LEN + kv0 + ((ch ^ (row&7))*8)),
        (AS3 void*)((char*)&Vs[buf][0] + (l*256 + wv*64)*16), 16, 0, 0);
    }
  };

  const int nt = 2*qt + 2;
  stage(0, 0);
  for (int t=0; t<nt; ++t){
    __syncthreads();
    if (t+1 < nt) stage((t+1)&1, (t+1)*64);
    const int kv0 = t*64;
    if (kv0 > q0w + 31) continue;
    const unsigned short* K_ = &Ks[t&1][0];
    const unsigned short* V_ = &Vs[t&1][0];

    f32x16 a0, a1;
    #pragma unroll
    for (int i=0;i<16;i++){ a0[i]=0.f; a1[i]=0.f; }
    #pragma unroll
    for (int st=0; st<8; ++st){
      int ch = (2*st + g) ^ (l31 & 15);
      bf16x8 k0 = *(const bf16x8*)&K_[ l31*128      + ch*8 ];
      int ch1 = (2*st + g) ^ ((32+l31) & 15);
      bf16x8 k1 = *(const bf16x8*)&K_[ (32+l31)*128 + ch1*8 ];
      a0 = __builtin_amdgcn_mfma_f32_32x32x16_bf16(k0, qf[st], a0, 0,0,0);
      a1 = __builtin_amdgcn_mfma_f32_32x32x16_bf16(k1, qf[st], a1, 0,0,0);
    }

    float p0[16], p1[16];
    const bool dm = (kv0 + 63 > q0w);
    const int lim = qg - kv0 - 4*g;
    #pragma unroll
    for (int i=0;i<16;i++){
      const int co = (i&3) + 8*(i>>2);
      float e0 = fmaf(a0[i], CS, -C0);
      float e1 = fmaf(a1[i], CS, -C0);
      if (dm){
        if (co      > lim) e0 = -200.f;
        if (co + 32 > lim) e1 = -200.f;
      }
      p0[i] = exp2f(fminf(e0, 60.f));
      p1[i] = exp2f(fminf(e1, 60.f));
    }
    {
      float u0 = (p0[0]+p0[1])+(p0[2]+p0[3]);
      float u1 = (p0[4]+p0[5])+(p0[6]+p0[7]);
      float u2 = (p0[8]+p0[9])+(p0[10]+p0[11]);
      float u3 = (p0[12]+p0[13])+(p0[14]+p0[15]);
      float v0 = (p1[0]+p1[1])+(p1[2]+p1[3]);
      float v1 = (p1[4]+p1[5])+(p1[6]+p1[7]);
      float v2 = (p1[8]+p1[9])+(p1[10]+p1[11]);
      float v3 = (p1[12]+p1[13])+(p1[14]+p1[15]);
      lsum += ((u0+u1)+(u2+u3)) + ((v0+v1)+(v2+v3));
    }

    bf16x8 pa[4];
    #pragma unroll
    for (int u=0; u<4; ++u){
      const float* P = (u<2) ? p0 : p1;
      const int i0 = 8*(u&1);
      unsigned int w0,w1,w2,w3;
      asm("v_cvt_pk_bf16_f32 %0, %1, %2" : "=v"(w0) : "v"(P[i0+0]), "v"(P[i0+1]));
      asm("v_cvt_pk_bf16_f32 %0, %1, %2" : "=v"(w1) : "v"(P[i0+2]), "v"(P[i0+3]));
      asm("v_cvt_pk_bf16_f32 %0, %1, %2" : "=v"(w2) : "v"(P[i0+4]), "v"(P[i0+5]));
      asm("v_cvt_pk_bf16_f32 %0, %1, %2" : "=v"(w3) : "v"(P[i0+6]), "v"(P[i0+7]));
      unsigned int r0 = __shfl_xor(g ? w0 : w2, 32);
      unsigned int r1 = __shfl_xor(g ? w1 : w3, 32);
      union { unsigned int u4[4]; bf16x8 v; } pk;
      pk.u4[0] = g ? r0 : w0;
      pk.u4[1] = g ? r1 : w1;
      pk.u4[2] = g ? w2 : r0;
      pk.u4[3] = g ? w3 : r1;
      pa[u] = pk.v;
    }

    #pragma unroll
    for (int u=0; u<4; ++u)
      #pragma unroll
      for (int db=0; db<4; ++db){
        int row = db*32 + l31;
        int ch = (2*u + g) ^ (row & 7);
        bf16x8 vb = *(const bf16x8*)&V_[row*64 + ch*8];
        oacc[db] = __builtin_amdgcn_mfma_f32_32x32x16_bf16(pa[u], vb, oacc[db], 0,0,0);
      }
  }

  float ls = lsum + __shfl_xor(lsum, 32);
  float inv = 1.0f / fmaxf(ls, 1e-30f);
  Ls[wv][l31] = inv;
  #pragma unroll
  for (int ib=0; ib<4; ++ib){
    float4 iv = *(const float4*)&Ls[wv][8*ib + 4*g];
    float ivv[4] = {iv.x, iv.y, iv.z, iv.w};
    #pragma unroll
    for (int c3=0; c3<4; ++c3){
      int row = 8*ib + 4*g + c3;
      #pragma unroll
      for (int db=0; db<4; ++db){
        AO[(size_t)(qb + wv*32 + row)*HID + h*HDIM + db*32 + l31] =
          f2bf(oacc[db][4*ib+c3] * ivv[c3]);
      }
    }
  }
}

// ---------------- launch ----------------
extern "C" void kernel_launch(void* const* d_in, const int* in_sizes, int n_in,
                              void* d_out, int out_size, void* d_ws, size_t ws_size,
                              hipStream_t stream){
  (void)in_sizes; (void)n_in; (void)out_size; (void)ws_size;
  const float* hs = (const float*)d_in[0];
  const float* Wq = (const float*)d_in[1];
  const float* Wk = (const float*)d_in[2];
  const float* Wv = (const float*)d_in[3];
  const float* Wo = (const float*)d_in[4];
  float* out = (float*)d_out;
  char* ws = (char*)d_ws;
  size_t off = 0;
  auto alloc = [&](size_t bytes)->void*{ void* p = ws + off; off += (bytes + 255) & ~(size_t)255; return p; };

  unsigned short* Hb    = (unsigned short*)alloc((size_t)S_LEN*HID*2);
  unsigned short* Wqkvb = (unsigned short*)alloc((size_t)QKVN*HID*2);
  unsigned short* Wob   = (unsigned short*)alloc((size_t)HID*HID*2);
  unsigned short* QKVb  = (unsigned short*)alloc((size_t)S_LEN*QKVN*2);
  unsigned short* AOb   = (unsigned short*)alloc((size_t)S_LEN*HID*2);
  unsigned short* Vtb   = (unsigned short*)alloc((size_t)NKVH*HDIM*S_LEN*2);
  float* cosT = (float*)alloc((size_t)S_LEN*64*4);
  float* sinT = (float*)alloc((size_t)S_LEN*64*4);

  // fused conversion of all inputs + rope table (one launch, grid-stride)
  cvt_all<<<2048, 256, 0, stream>>>(hs, Wq, Wk, Wv, Wo, Hb, Wqkvb, Wob, cosT, sinT);

  // fused QKV projection: BM=128, BN=192, 4 waves 2Mx2N -> 512 blocks (2/CU)
  gemm_fr<128,192,2,2,0><<<dim3(QKVN/192, S_LEN/128), 256, 0, stream>>>(Hb, Wqkvb, QKVb, S_LEN, QKVN, HID);

  // merged V-transpose (blocks 0..255) + Q/K rope (blocks 256..)
  {
    int total = S_LEN*NHEADS*64 + S_LEN*NKVH*64;
    int ropeBlocks = (total + 255) / 256;
    trope<<<256 + ropeBlocks, 256, 0, stream>>>(cosT, sinT, QKVb, Vtb);
  }

  // attention: 16 q-tiles of 128 (descending) x 32 heads = 512 blocks
  attn_fwd3<<<dim3(512), 256, 0, stream>>>(QKVb, Vtb, AOb);

  // output projection: BM=128, BN=128, 4 waves 2Mx2N -> 512 blocks (2/CU)
  gemm_fr<128,128,2,2,1><<<dim3(HID/128, S_LEN/128), 256, 0, stream>>>(AOb, Wob, out, S_LEN, HID, HID);
}